// Round 1
// 324.921 us; speedup vs baseline: 1.0744x; 1.0744x over previous
//
#include <hip/hip_runtime.h>

typedef unsigned short u16;
typedef __attribute__((ext_vector_type(8))) short bf16x8;
typedef __attribute__((ext_vector_type(4))) float f32x4;

#define D_MODEL 1024
#define T_SEQ   2048
#define NB      4
#define NH      16
#define DKH     64

__device__ __forceinline__ u16 f2bf(float x) {
  union { float f; unsigned u; } v; v.f = x;
  unsigned r = v.u + 0x7fffu + ((v.u >> 16) & 1u);
  return (u16)(r >> 16);
}
__device__ __forceinline__ unsigned pack2(float a, float b) {
  return (unsigned)f2bf(a) | ((unsigned)f2bf(b) << 16);
}
// HW packed f32->bf16 (RNE, bit-identical to f2bf for normals). Non-volatile:
// let the scheduler move it freely.
__device__ __forceinline__ unsigned cvtpk2(float a, float b) {
  unsigned r;
  asm("v_cvt_pk_bf16_f32 %0, %1, %2" : "=v"(r) : "v"(a), "v"(b));
  return r;
}
__device__ __forceinline__ float fexp2(float x) {
#if __has_builtin(__builtin_amdgcn_exp2f)
  return __builtin_amdgcn_exp2f(x);
#else
  return __expf(x * 0.6931471805599453f);
#endif
}

// async global->LDS, 16B per lane. LDS dest = wave-uniform base + lane*16.
__device__ __forceinline__ void gload16(const void* g, void* l) {
  __builtin_amdgcn_global_load_lds(
      (const __attribute__((address_space(1))) unsigned*)g,
      (__attribute__((address_space(3))) unsigned*)l, 16, 0, 0);
}

// ---------------- cast 4 weight matrices fp32 -> bf16 ----------------
__global__ void cast_w4(const float* __restrict__ s0, const float* __restrict__ s1,
                        const float* __restrict__ s2, const float* __restrict__ s3,
                        u16* __restrict__ o0, u16* __restrict__ o1,
                        u16* __restrict__ o2, u16* __restrict__ o3) {
  const int which = blockIdx.y;
  const float* s = which == 0 ? s0 : which == 1 ? s1 : which == 2 ? s2 : s3;
  u16* o = which == 0 ? o0 : which == 1 ? o1 : which == 2 ? o2 : o3;
  int i = ((int)blockIdx.x * 256 + (int)threadIdx.x) * 4;
  float4 v = *(const float4*)(s + i);
  uint2 u; u.x = pack2(v.x, v.y); u.y = pack2(v.z, v.w);
  *(uint2*)(o + i) = u;
}

// ---------------- fused QKV projection v9: m97-style single-buffer loop ----------------
// grid (64, 8, 3); z selects (q,k,v). C = A@W^T + bias, bf16 out.
// 128x128 tile, 4 waves (2x2 of 64x64), BK=64, 32 KB LDS (single buffer) ->
// 3 blocks/CU instead of v8's 2 (64 KB dbuf). Two barriers per K-step; the
// inter-block wave overlap covers the drain stall (m97 structure, ~900 TF class).
// A is fp32: register-prefetched one K-step ahead (issued AFTER the drain
// barrier so its latency hides under the MFMA section, not the barrier), then
// packed with v_cvt_pk_bf16_f32 (1 inst per pair vs ~9 for bit-twiddle RNE).
// Q output pre-scaled by log2(e)/8 (bare-exp2 softmax downstream).
__global__ __launch_bounds__(256, 3) void gemm_qkv(
    const float* __restrict__ qin, const float* __restrict__ kin, const float* __restrict__ vin,
    const u16* __restrict__ wq, const u16* __restrict__ wk, const u16* __restrict__ wv,
    const float* __restrict__ bqp, const float* __restrict__ bkp, const float* __restrict__ bvp,
    u16* __restrict__ Xq, u16* __restrict__ Xk, u16* __restrict__ Xv) {
  const int z = blockIdx.z;
  const float* A = z == 0 ? qin : z == 1 ? kin : vin;
  const u16* W = z == 0 ? wq : z == 1 ? wk : wv;
  const float* bias = z == 0 ? bqp : z == 1 ? bkp : bvp;
  u16* C = z == 0 ? Xq : z == 1 ? Xk : Xv;
  const float osc = z == 0 ? 0.18033688011112042f : 1.0f;  // log2(e)/8
  const int K = 1024, N = 1024;

  __shared__ __align__(16) u16 As[8192];   // 16 KB
  __shared__ __align__(16) u16 Bs[8192];   // 16 KB
  const int tid = threadIdx.x;
  const int w = tid >> 6, lane = tid & 63;
  const int wm = w & 1, wn = w >> 1;
  const int l15 = lane & 15, quad = lane >> 4;
  const int l8 = lane >> 3, l7 = lane & 7;
  const int m0 = blockIdx.x * 128, n0 = blockIdx.y * 128;
  const int sb = l7 ^ l8;   // source col-block for swizzled staging

  // A source: inst j covers rows w*32+j*8+l8, src block sb (fp32)
  const float* gA = A + (size_t)(m0 + w * 32 + l8) * K + sb * 8;
  // B source: same mapping in bf16
  const u16* gB = W + (size_t)(n0 + w * 32 + l8) * K + sb * 8;

  f32x4 zero4 = {0.f, 0.f, 0.f, 0.f};
  f32x4 acc[4][4];
#pragma unroll
  for (int i = 0; i < 4; ++i)
#pragma unroll
    for (int j = 0; j < 4; ++j) acc[i][j] = zero4;

  // preload K-step 0: A fp32 -> regs
  float4 a0[4], a1[4];
#pragma unroll
  for (int j = 0; j < 4; ++j) {
    const float* p = gA + (size_t)(j * 8) * K;
    a0[j] = *(const float4*)p;
    a1[j] = *(const float4*)(p + 4);
  }

  for (int kbi = 0; kbi < 16; ++kbi) {
    if (kbi) __syncthreads();   // all waves done reading tile kbi-1

    // issue B DMA first (long latency, overlaps the pack below)
#pragma unroll
    for (int j = 0; j < 4; ++j)
      gload16(gB + kbi * 64 + (size_t)(j * 8) * K, Bs + (w * 32 + j * 8) * 64);

    // pack + conflict-free swizzled write of As (dest block = l7)
#pragma unroll
    for (int j = 0; j < 4; ++j) {
      uint4 wv4;
      wv4.x = cvtpk2(a0[j].x, a0[j].y); wv4.y = cvtpk2(a0[j].z, a0[j].w);
      wv4.z = cvtpk2(a1[j].x, a1[j].y); wv4.w = cvtpk2(a1[j].z, a1[j].w);
      *(uint4*)(As + (w * 32 + j * 8 + l8) * 64 + l7 * 8) = wv4;
    }
    __syncthreads();   // drains ds_write (lgkm) + B DMA (vmcnt)

    // A prefetch for kbi+1: issued after the drain barrier so the barrier's
    // vmcnt(0) doesn't wait on it; completes under the MFMA section (A panels
    // are shared by 8 column-blocks -> mostly L2 hits).
    if (kbi < 15) {
      const int kb2 = (kbi + 1) * 64;
#pragma unroll
      for (int j = 0; j < 4; ++j) {
        const float* p = gA + kb2 + (size_t)(j * 8) * K;
        a0[j] = *(const float4*)p;
        a1[j] = *(const float4*)(p + 4);
      }
    }

#pragma unroll
    for (int ks = 0; ks < 2; ++ks) {
      const int sw = ((ks * 4 + quad) ^ (l15 & 7)) * 8;
      bf16x8 af[4], bfr[4];
#pragma unroll
      for (int i = 0; i < 4; ++i)
        af[i] = *(const bf16x8*)(As + (wm * 64 + i * 16 + l15) * 64 + sw);
#pragma unroll
      for (int i = 0; i < 4; ++i)
        bfr[i] = *(const bf16x8*)(Bs + (wn * 64 + i * 16 + l15) * 64 + sw);
#pragma unroll
      for (int mi = 0; mi < 4; ++mi)
#pragma unroll
        for (int ni = 0; ni < 4; ++ni)
          acc[mi][ni] = __builtin_amdgcn_mfma_f32_16x16x32_bf16(af[mi], bfr[ni], acc[mi][ni], 0, 0, 0);
    }
  }

#pragma unroll
  for (int ni = 0; ni < 4; ++ni) {
    int col = n0 + wn * 64 + ni * 16 + l15;
    float bv = bias[col];
#pragma unroll
    for (int mi = 0; mi < 4; ++mi) {
      int row = m0 + wm * 64 + mi * 16 + quad * 4;
#pragma unroll
      for (int r = 0; r < 4; ++r)
        C[(size_t)(row + r) * N + col] = f2bf((acc[mi][ni][r] + bv) * osc);
    }
  }
}

// ---------------- O-projection v9: m97-style single-buffer, both operands DMA ----------------
__global__ __launch_bounds__(256) void gemm_nt_f32out(const u16* __restrict__ Ab,
                                                      const u16* __restrict__ W,
                                                      const float* __restrict__ bias,
                                                      float* __restrict__ Cp,
                                                      int M, int N, int K) {
  __shared__ __align__(16) u16 As[8192];
  __shared__ __align__(16) u16 Bs[8192];
  const int tid = threadIdx.x;
  const int w = tid >> 6, lane = tid & 63;
  const int wm = w & 1, wn = w >> 1;
  const int l15 = lane & 15, quad = lane >> 4;
  const int l8 = lane >> 3, l7 = lane & 7;
  const int m0 = blockIdx.x * 128, n0 = blockIdx.y * 128;
  const int sb = l7 ^ l8;

  const u16* gA = Ab + (size_t)(m0 + w * 32 + l8) * K + sb * 8;
  const u16* gB = W  + (size_t)(n0 + w * 32 + l8) * K + sb * 8;

  f32x4 zero4 = {0.f, 0.f, 0.f, 0.f};
  f32x4 acc[4][4];
#pragma unroll
  for (int i = 0; i < 4; ++i)
#pragma unroll
    for (int j = 0; j < 4; ++j) acc[i][j] = zero4;

  for (int kbi = 0; kbi < 16; ++kbi) {
    if (kbi) __syncthreads();   // all waves done reading tile kbi-1
    const int kb = kbi * 64;
#pragma unroll
    for (int j = 0; j < 4; ++j) {
      gload16(gA + kb + (size_t)(j * 8) * K, As + (w * 32 + j * 8) * 64);
      gload16(gB + kb + (size_t)(j * 8) * K, Bs + (w * 32 + j * 8) * 64);
    }
    __syncthreads();   // drain DMA

#pragma unroll
    for (int ks = 0; ks < 2; ++ks) {
      const int sw = ((ks * 4 + quad) ^ (l15 & 7)) * 8;
      bf16x8 af[4], bfr[4];
#pragma unroll
      for (int i = 0; i < 4; ++i)
        af[i] = *(const bf16x8*)(As + (wm * 64 + i * 16 + l15) * 64 + sw);
#pragma unroll
      for (int i = 0; i < 4; ++i)
        bfr[i] = *(const bf16x8*)(Bs + (wn * 64 + i * 16 + l15) * 64 + sw);
#pragma unroll
      for (int mi = 0; mi < 4; ++mi)
#pragma unroll
        for (int ni = 0; ni < 4; ++ni)
          acc[mi][ni] = __builtin_amdgcn_mfma_f32_16x16x32_bf16(af[mi], bfr[ni], acc[mi][ni], 0, 0, 0);
    }
  }

#pragma unroll
  for (int ni = 0; ni < 4; ++ni) {
    int col = n0 + wn * 64 + ni * 16 + l15;
    float bv = bias[col];
#pragma unroll
    for (int mi = 0; mi < 4; ++mi) {
      int row = m0 + wm * 64 + mi * 16 + quad * 4;
#pragma unroll
      for (int r = 0; r < 4; ++r)
        Cp[(size_t)(row + r) * N + col] = acc[mi][ni][r] + bv;
    }
  }
}

// ---------------- causal flash attention (r7 structure; pack2 -> v_cvt_pk) ----------------
__global__ __launch_bounds__(512, 2) void attn_fwd(const u16* __restrict__ Xq,
                                                   const u16* __restrict__ Xk,
                                                   const u16* __restrict__ Xv,
                                                   u16* __restrict__ O) {
  __shared__ __align__(16) char smem[65536];

  const int xp = blockIdx.x;                // 0..7
  const int h = blockIdx.y, b = blockIdx.z;
  const int tid = threadIdx.x;
  const int w = tid >> 6, lane = tid & 63;
  const int half = w >> 2, wl = w & 3;
  const int l15 = lane & 15, quad = lane >> 4;
  const size_t base = (size_t)b * T_SEQ * D_MODEL;
  const int hd = h * DKH;

  u16* KtH = (u16*)(smem + half * 32768);
  u16* VtH = (u16*)(smem + half * 32768 + 16384);
  float* ML = (float*)(smem + 16384);
  float* MO = (float*)(smem + 32768);

  const int krow = lane >> 3;
  const int kcol = ((lane & 7) ^ krow) * 8;
  const u16* gK = Xk + base + (size_t)(wl * 16 + krow) * D_MODEL + hd + kcol;
  const int vkey = lane;
  const int skey = (vkey & 0x20) | ((vkey & 0xC) << 1) | ((vkey & 0x10) >> 2) | (vkey & 3);
  const int scb = skey >> 3, sci = skey & 7;
  const u16* gV = Xv + base + (size_t)vkey * D_MODEL + hd + wl * 16;

  bf16x8 bones;
#pragma unroll
  for (int i = 0; i < 8; ++i) bones[i] = (short)0x3F80;  // bf16 1.0

  f32x4 zero4 = {0.f, 0.f, 0.f, 0.f};
  int tcnt = 0;

  {
    const u16* gk0 = gK + (size_t)(half * 64) * D_MODEL;
    gload16(gk0, KtH + (wl * 16) * 64);
    gload16(gk0 + (size_t)8 * D_MODEL, KtH + (wl * 16 + 8) * 64);
  }
  const u16* gv0 = gV + (size_t)(half * 64) * D_MODEL;
  uint4 va0 = *(const uint4*)gv0;
  uint4 va1 = *(const uint4*)(gv0 + 8);

  for (int ph = 0; ph < 2; ++ph) {
    const int qt = ph ? xp : 15 - xp;
    const int q0 = qt << 7;
    const int rowb0 = q0 + wl * 32;

    bf16x8 bq[2][2];
#pragma unroll
    for (int mi = 0; mi < 2; ++mi)
#pragma unroll
      for (int ks = 0; ks < 2; ++ks)
        bq[mi][ks] = *(const bf16x8*)(Xq + base + (size_t)(rowb0 + mi * 16 + l15) * D_MODEL
                                      + hd + ks * 32 + quad * 8);

    f32x4 o[4][2], ol[2];
#pragma unroll
    for (int di = 0; di < 4; ++di)
#pragma unroll
      for (int mi = 0; mi < 2; ++mi) o[di][mi] = zero4;
#pragma unroll
    for (int mi = 0; mi < 2; ++mi) ol[mi] = zero4;

    const int cnt = qt + 1;

    if (ph == 1 && half == 1) {
      const int fb = tcnt & 1;
      const u16* gk1 = gK + (size_t)64 * D_MODEL;
      gload16(gk1, KtH + fb * 4096 + (wl * 16) * 64);
      gload16(gk1 + (size_t)8 * D_MODEL, KtH + fb * 4096 + (wl * 16 + 8) * 64);
    }

    for (int i = 0; i < cnt; ++i, ++tcnt) {
      const int k0 = (half + 2 * i) * 64;
      const int buf = tcnt & 1;
      u16* ktb = KtH + buf * 4096;
      u16* vtb = VtH + buf * 4096;

      {
        union { uint4 u; u16 hh[8]; } u0, u1;
        u0.u = va0; u1.u = va1;
#pragma unroll
        for (int ii = 0; ii < 8; ++ii) {
          vtb[(wl * 16 + ii) * 64 + ((scb ^ ii) << 3) + sci] = u0.hh[ii];
          vtb[(wl * 16 + 8 + ii) * 64 + ((scb ^ ii) << 3) + sci] = u1.hh[ii];
        }
      }
      __syncthreads();

      const bool inph = (i + 1 < cnt);
      if (inph || ph == 0) {
        const int k0n = inph ? k0 + 128 : half * 64;
        if (inph || half == 0) {
          const u16* gk2 = gK + (size_t)k0n * D_MODEL;
          u16* ktn = KtH + (1 - buf) * 4096;
          gload16(gk2, ktn + (wl * 16) * 64);
          gload16(gk2 + (size_t)8 * D_MODEL, ktn + (wl * 16 + 8) * 64);
        }
        const u16* gv2 = gV + (size_t)k0n * D_MODEL;
        va0 = *(const uint4*)gv2;
        va1 = *(const uint4*)(gv2 + 8);
      }

      f32x4 st[4][2];
#pragma unroll
      for (int ni = 0; ni < 4; ++ni) {
        const u16* kr = ktb + (ni * 16 + l15) * 64;
        bf16x8 a0 = *(const bf16x8*)(kr + ((quad ^ (l15 & 7)) << 3));
        bf16x8 a1 = *(const bf16x8*)(kr + (((4 + quad) ^ (l15 & 7)) << 3));
#pragma unroll
        for (int mi = 0; mi < 2; ++mi) {
          f32x4 t = zero4;
          t = __builtin_amdgcn_mfma_f32_16x16x32_bf16(a0, bq[mi][0], t, 0, 0, 0);
          t = __builtin_amdgcn_mfma_f32_16x16x32_bf16(a1, bq[mi][1], t, 0, 0, 0);
          st[ni][mi] = t;
        }
      }

      bf16x8 bp[2][2];
#pragma unroll
      for (int mi = 0; mi < 2; ++mi) {
        const int qa = rowb0 + mi * 16 + l15;
        if (k0 + 63 > rowb0 + mi * 16) {
#pragma unroll
          for (int ni = 0; ni < 4; ++ni)
#pragma unroll
            for (int r = 0; r < 4; ++r)
              if (k0 + ni * 16 + quad * 4 + r > qa) st[ni][mi][r] = -1e30f;
        }
        float p[4][4];
#pragma unroll
        for (int ni = 0; ni < 4; ++ni)
#pragma unroll
          for (int r = 0; r < 4; ++r)
            p[ni][r] = fexp2(st[ni][mi][r]);
#pragma unroll
        for (int js = 0; js < 2; ++js) {
          union { bf16x8 v; unsigned d[4]; } ub;
          ub.d[0] = cvtpk2(p[2 * js][0], p[2 * js][1]);
          ub.d[1] = cvtpk2(p[2 * js][2], p[2 * js][3]);
          ub.d[2] = cvtpk2(p[2 * js + 1][0], p[2 * js + 1][1]);
          ub.d[3] = cvtpk2(p[2 * js + 1][2], p[2 * js + 1][3]);
          bp[mi][js] = ub.v;
        }
      }

#pragma unroll
      for (int js = 0; js < 2; ++js) {
        bf16x8 av[4];
#pragma unroll
        for (int di = 0; di < 4; ++di)
          av[di] = *(const bf16x8*)(vtb + (di * 16 + l15) * 64
                                    + (((js * 4 + quad) ^ (l15 & 7)) << 3));
#pragma unroll
        for (int di = 0; di < 4; ++di)
#pragma unroll
          for (int mi = 0; mi < 2; ++mi)
            o[di][mi] = __builtin_amdgcn_mfma_f32_16x16x32_bf16(av[di], bp[mi][js], o[di][mi], 0, 0, 0);
#pragma unroll
        for (int mi = 0; mi < 2; ++mi)
          ol[mi] = __builtin_amdgcn_mfma_f32_16x16x32_bf16(bones, bp[mi][js], ol[mi], 0, 0, 0);
      }
    }

    __syncthreads();
    if (half == 1) {
#pragma unroll
      for (int mi = 0; mi < 2; ++mi) {
        const int ql = wl * 32 + mi * 16 + l15;
        if (quad == 0) ML[ql] = ol[mi][0];
#pragma unroll
        for (int di = 0; di < 4; ++di)
#pragma unroll
          for (int r = 0; r < 4; ++r) {
            const int d = di * 16 + quad * 4 + r;
            MO[ql * 64 + (d ^ ((ql & 7) << 3))] = o[di][mi][r];
          }
      }
    }
    __syncthreads();
    if (half == 0) {
#pragma unroll
      for (int mi = 0; mi < 2; ++mi) {
        const int ql = wl * 32 + mi * 16 + l15;
        const float inv = 1.0f / (ol[mi][0] + ML[ql]);
        const size_t qa = q0 + ql;
#pragma unroll
        for (int di = 0; di < 4; ++di) {
          float t[4];
#pragma unroll
          for (int r = 0; r < 4; ++r) {
            const int d = di * 16 + quad * 4 + r;
            t[r] = (o[di][mi][r] + MO[ql * 64 + (d ^ ((ql & 7) << 3))]) * inv;
          }
          uint2 s2;
          s2.x = cvtpk2(t[0], t[1]);
          s2.y = cvtpk2(t[2], t[3]);
          *(uint2*)(O + base + qa * D_MODEL + hd + di * 16 + quad * 4) = s2;
        }
      }
    }
    __syncthreads();
  }
}

// ---------------- launch ----------------
extern "C" void kernel_launch(void* const* d_in, const int* in_sizes, int n_in,
                              void* d_out, int out_size, void* d_ws, size_t ws_size,
                              hipStream_t stream) {
  const float* q   = (const float*)d_in[0];
  const float* k   = (const float*)d_in[1];
  const float* v   = (const float*)d_in[2];
  const float* w_q = (const float*)d_in[4];  const float* b_q = (const float*)d_in[5];
  const float* w_k = (const float*)d_in[6];  const float* b_k = (const float*)d_in[7];
  const float* w_v = (const float*)d_in[8];  const float* b_v = (const float*)d_in[9];
  const float* w_o = (const float*)d_in[10]; const float* b_o = (const float*)d_in[11];

  u16* ws = (u16*)d_ws;
  const size_t NTD = (size_t)NB * T_SEQ * D_MODEL;   // 8388608
  const size_t WSZ = (size_t)D_MODEL * D_MODEL;      // 1048576
  u16* wqb = ws;
  u16* wkb = wqb + WSZ;
  u16* wvb = wkb + WSZ;
  u16* wob = wvb + WSZ;
  u16* Xq  = wob + WSZ;
  u16* Xk  = Xq + NTD;
  u16* Xv  = Xk + NTD;
  u16* Ob  = Xv + NTD;
  // total ws: 4*2MB + 4*16.78MB = 75.5 MB

  cast_w4<<<dim3(WSZ / 1024, 4), 256, 0, stream>>>(w_q, w_k, w_v, w_o, wqb, wkb, wvb, wob);

  gemm_qkv<<<dim3(64, 8, 3), 256, 0, stream>>>(q, k, v, wqb, wkb, wvb,
                                               b_q, b_k, b_v, Xq, Xk, Xv);

  attn_fwd<<<dim3(8, NH, NB), 512, 0, stream>>>(Xq, Xk, Xv, Ob);

  gemm_nt_f32out<<<dim3(64, 8), 256, 0, stream>>>(Ob, wob, b_o, (float*)d_out,
                                                  8192, 1024, 1024);
}

// Round 4
// 316.478 us; speedup vs baseline: 1.1031x; 1.0267x over previous
//
#include <hip/hip_runtime.h>

typedef unsigned short u16;
typedef __attribute__((ext_vector_type(8))) short bf16x8;
typedef __attribute__((ext_vector_type(4))) float f32x4;

#define D_MODEL 1024
#define T_SEQ   2048
#define NB      4
#define NH      16
#define DKH     64

__device__ __forceinline__ u16 f2bf(float x) {
  union { float f; unsigned u; } v; v.f = x;
  unsigned r = v.u + 0x7fffu + ((v.u >> 16) & 1u);
  return (u16)(r >> 16);
}
__device__ __forceinline__ unsigned pack2(float a, float b) {
  return (unsigned)f2bf(a) | ((unsigned)f2bf(b) << 16);
}
// HW packed f32->bf16 (RNE).
__device__ __forceinline__ unsigned cvtpk2(float a, float b) {
  unsigned r;
  asm("v_cvt_pk_bf16_f32 %0, %1, %2" : "=v"(r) : "v"(a), "v"(b));
  return r;
}
__device__ __forceinline__ float fexp2(float x) {
#if __has_builtin(__builtin_amdgcn_exp2f)
  return __builtin_amdgcn_exp2f(x);
#else
  return __expf(x * 0.6931471805599453f);
#endif
}

// async global->LDS, 16B per lane. LDS dest = wave-uniform base + lane*16.
__device__ __forceinline__ void gload16(const void* g, void* l) {
  __builtin_amdgcn_global_load_lds(
      (const __attribute__((address_space(1))) unsigned*)g,
      (__attribute__((address_space(3))) unsigned*)l, 16, 0, 0);
}

// ---------------- cast 4 weight matrices fp32 -> bf16 ----------------
__global__ void cast_w4(const float* __restrict__ s0, const float* __restrict__ s1,
                        const float* __restrict__ s2, const float* __restrict__ s3,
                        u16* __restrict__ o0, u16* __restrict__ o1,
                        u16* __restrict__ o2, u16* __restrict__ o3) {
  const int which = blockIdx.y;
  const float* s = which == 0 ? s0 : which == 1 ? s1 : which == 2 ? s2 : s3;
  u16* o = which == 0 ? o0 : which == 1 ? o1 : which == 2 ? o2 : o3;
  int i = ((int)blockIdx.x * 256 + (int)threadIdx.x) * 4;
  float4 v = *(const float4*)(s + i);
  uint2 u; u.x = pack2(v.x, v.y); u.y = pack2(v.z, v.w);
  *(uint2*)(o + i) = u;
}

// ---------------- fused QKV projection v12: dbuf-B pipeline (ONLY change vs round-1) ----
// grid (64, 8, 3); z selects (q,k,v). C = A@W^T + bias, bf16 out, row-major.
// 128x128 tile, 4 waves, BK=64. LDS = As 16K (single) + Bs 2x16K (dbuf) = 48 KB
// -> 3 blocks/CU. B-DMA for step k+1 is issued AFTER barrier-2 of step k, stays
// in flight across the entire MFMA(k) section, and is drained by step k+1's
// barrier-1 (__syncthreads' vmcnt(0)) -> ~zero exposed B latency.
// All sync via __syncthreads (full compiler+HW ordering).
// A fp32 reg-prefetched one step ahead, packed via v_cvt_pk_bf16_f32.
// Q output pre-scaled by log2(e)/8 (bare-exp2 softmax downstream).
__global__ __launch_bounds__(256, 3) void gemm_qkv(
    const float* __restrict__ qin, const float* __restrict__ kin, const float* __restrict__ vin,
    const u16* __restrict__ wq, const u16* __restrict__ wk, const u16* __restrict__ wv,
    const float* __restrict__ bqp, const float* __restrict__ bkp, const float* __restrict__ bvp,
    u16* __restrict__ Xq, u16* __restrict__ Xk, u16* __restrict__ Xv) {
  const int z = blockIdx.z;
  const float* A = z == 0 ? qin : z == 1 ? kin : vin;
  const u16* W = z == 0 ? wq : z == 1 ? wk : wv;
  const float* bias = z == 0 ? bqp : z == 1 ? bkp : bvp;
  u16* C = z == 0 ? Xq : z == 1 ? Xk : Xv;
  const float osc = z == 0 ? 0.18033688011112042f : 1.0f;  // log2(e)/8
  const int K = 1024, N = 1024;

  __shared__ __align__(16) char smem[49152];
  u16* As  = (u16*)smem;             // 16 KB, single buffer
  u16* Bs0 = (u16*)(smem + 16384);   // 16 KB
  u16* Bs1 = (u16*)(smem + 32768);   // 16 KB

  const int tid = threadIdx.x;
  const int w = tid >> 6, lane = tid & 63;
  const int wm = w & 1, wn = w >> 1;
  const int l15 = lane & 15, quad = lane >> 4;
  const int l8 = lane >> 3, l7 = lane & 7;
  const int m0 = blockIdx.x * 128, n0 = blockIdx.y * 128;
  const int sb = l7 ^ l8;   // source col-block for swizzled staging

  const float* gA = A + (size_t)(m0 + w * 32 + l8) * K + sb * 8;
  const u16* gB = W + (size_t)(n0 + w * 32 + l8) * K + sb * 8;

  f32x4 zero4 = {0.f, 0.f, 0.f, 0.f};
  f32x4 acc[4][4];
#pragma unroll
  for (int i = 0; i < 4; ++i)
#pragma unroll
    for (int j = 0; j < 4; ++j) acc[i][j] = zero4;

  // preload: B(0) DMA -> Bs0; A(0) fp32 -> regs
#pragma unroll
  for (int j = 0; j < 4; ++j)
    gload16(gB + (size_t)(j * 8) * K, Bs0 + (w * 32 + j * 8) * 64);
  float4 a0[4], a1[4];
#pragma unroll
  for (int j = 0; j < 4; ++j) {
    const float* p = gA + (size_t)(j * 8) * K;
    a0[j] = *(const float4*)p;
    a1[j] = *(const float4*)(p + 4);
  }

  for (int kbi = 0; kbi < 16; ++kbi) {
    u16* Bc = (kbi & 1) ? Bs1 : Bs0;
    u16* Bn = (kbi & 1) ? Bs0 : Bs1;

    if (kbi) __syncthreads();   // B1: all reads of step kbi-1 done (own lgkm
                                // drained pre-barrier); drains B(kbi) DMA +
                                // A(kbi) loads issued during step kbi-1

    // pack + conflict-free swizzled write of As (dest block = l7)
#pragma unroll
    for (int j = 0; j < 4; ++j) {
      uint4 wv4;
      wv4.x = cvtpk2(a0[j].x, a0[j].y); wv4.y = cvtpk2(a0[j].z, a0[j].w);
      wv4.z = cvtpk2(a1[j].x, a1[j].y); wv4.w = cvtpk2(a1[j].z, a1[j].w);
      *(uint4*)(As + (w * 32 + j * 8 + l8) * 64 + l7 * 8) = wv4;
    }
    __syncthreads();            // B2: As writes (and step-0 B DMA) visible

    if (kbi < 15) {
      const int kb2 = (kbi + 1) * 64;
#pragma unroll
      for (int j = 0; j < 4; ++j)
        gload16(gB + kb2 + (size_t)(j * 8) * K, Bn + (w * 32 + j * 8) * 64);
#pragma unroll
      for (int j = 0; j < 4; ++j) {
        const float* p = gA + kb2 + (size_t)(j * 8) * K;
        a0[j] = *(const float4*)p;
        a1[j] = *(const float4*)(p + 4);
      }
      __builtin_amdgcn_sched_barrier(0);   // keep issues ahead of the MFMA section
    }

#pragma unroll
    for (int ks = 0; ks < 2; ++ks) {
      const int sw = ((ks * 4 + quad) ^ (l15 & 7)) * 8;
      bf16x8 af[4], bfr[4];
#pragma unroll
      for (int i = 0; i < 4; ++i)
        af[i] = *(const bf16x8*)(As + (wm * 64 + i * 16 + l15) * 64 + sw);
#pragma unroll
      for (int i = 0; i < 4; ++i)
        bfr[i] = *(const bf16x8*)(Bc + (wn * 64 + i * 16 + l15) * 64 + sw);
#pragma unroll
      for (int mi = 0; mi < 4; ++mi)
#pragma unroll
        for (int ni = 0; ni < 4; ++ni)
          acc[mi][ni] = __builtin_amdgcn_mfma_f32_16x16x32_bf16(af[mi], bfr[ni], acc[mi][ni], 0, 0, 0);
    }
  }

#pragma unroll
  for (int ni = 0; ni < 4; ++ni) {
    int col = n0 + wn * 64 + ni * 16 + l15;
    float bv = bias[col];
#pragma unroll
    for (int mi = 0; mi < 4; ++mi) {
      int row = m0 + wm * 64 + mi * 16 + quad * 4;
#pragma unroll
      for (int r = 0; r < 4; ++r)
        C[(size_t)(row + r) * N + col] = f2bf((acc[mi][ni][r] + bv) * osc);
    }
  }
}

// ---------------- O-projection v9 (round-1 passing version, unchanged) ----------------
__global__ __launch_bounds__(256) void gemm_nt_f32out(const u16* __restrict__ Ab,
                                                      const u16* __restrict__ W,
                                                      const float* __restrict__ bias,
                                                      float* __restrict__ Cp,
                                                      int M, int N, int K) {
  __shared__ __align__(16) u16 As[8192];
  __shared__ __align__(16) u16 Bs[8192];
  const int tid = threadIdx.x;
  const int w = tid >> 6, lane = tid & 63;
  const int wm = w & 1, wn = w >> 1;
  const int l15 = lane & 15, quad = lane >> 4;
  const int l8 = lane >> 3, l7 = lane & 7;
  const int m0 = blockIdx.x * 128, n0 = blockIdx.y * 128;
  const int sb = l7 ^ l8;

  const u16* gA = Ab + (size_t)(m0 + w * 32 + l8) * K + sb * 8;
  const u16* gB = W  + (size_t)(n0 + w * 32 + l8) * K + sb * 8;

  f32x4 zero4 = {0.f, 0.f, 0.f, 0.f};
  f32x4 acc[4][4];
#pragma unroll
  for (int i = 0; i < 4; ++i)
#pragma unroll
    for (int j = 0; j < 4; ++j) acc[i][j] = zero4;

  for (int kbi = 0; kbi < 16; ++kbi) {
    if (kbi) __syncthreads();
    const int kb = kbi * 64;
#pragma unroll
    for (int j = 0; j < 4; ++j) {
      gload16(gA + kb + (size_t)(j * 8) * K, As + (w * 32 + j * 8) * 64);
      gload16(gB + kb + (size_t)(j * 8) * K, Bs + (w * 32 + j * 8) * 64);
    }
    __syncthreads();   // drain DMA

#pragma unroll
    for (int ks = 0; ks < 2; ++ks) {
      const int sw = ((ks * 4 + quad) ^ (l15 & 7)) * 8;
      bf16x8 af[4], bfr[4];
#pragma unroll
      for (int i = 0; i < 4; ++i)
        af[i] = *(const bf16x8*)(As + (wm * 64 + i * 16 + l15) * 64 + sw);
#pragma unroll
      for (int i = 0; i < 4; ++i)
        bfr[i] = *(const bf16x8*)(Bs + (wn * 64 + i * 16 + l15) * 64 + sw);
#pragma unroll
      for (int mi = 0; mi < 4; ++mi)
#pragma unroll
        for (int ni = 0; ni < 4; ++ni)
          acc[mi][ni] = __builtin_amdgcn_mfma_f32_16x16x32_bf16(af[mi], bfr[ni], acc[mi][ni], 0, 0, 0);
    }
  }

#pragma unroll
  for (int ni = 0; ni < 4; ++ni) {
    int col = n0 + wn * 64 + ni * 16 + l15;
    float bv = bias[col];
#pragma unroll
    for (int mi = 0; mi < 4; ++mi) {
      int row = m0 + wm * 64 + mi * 16 + quad * 4;
#pragma unroll
      for (int r = 0; r < 4; ++r)
        Cp[(size_t)(row + r) * N + col] = acc[mi][ni][r] + bv;
    }
  }
}

// ---------------- causal flash attention (round-1 passing version, unchanged) ----------
__global__ __launch_bounds__(512, 2) void attn_fwd(const u16* __restrict__ Xq,
                                                   const u16* __restrict__ Xk,
                                                   const u16* __restrict__ Xv,
                                                   u16* __restrict__ O) {
  __shared__ __align__(16) char smem[65536];

  const int xp = blockIdx.x;                // 0..7
  const int h = blockIdx.y, b = blockIdx.z;
  const int tid = threadIdx.x;
  const int w = tid >> 6, lane = tid & 63;
  const int half = w >> 2, wl = w & 3;
  const int l15 = lane & 15, quad = lane >> 4;
  const size_t base = (size_t)b * T_SEQ * D_MODEL;
  const int hd = h * DKH;

  u16* KtH = (u16*)(smem + half * 32768);
  u16* VtH = (u16*)(smem + half * 32768 + 16384);
  float* ML = (float*)(smem + 16384);
  float* MO = (float*)(smem + 32768);

  const int krow = lane >> 3;
  const int kcol = ((lane & 7) ^ krow) * 8;
  const u16* gK = Xk + base + (size_t)(wl * 16 + krow) * D_MODEL + hd + kcol;
  const int vkey = lane;
  const int skey = (vkey & 0x20) | ((vkey & 0xC) << 1) | ((vkey & 0x10) >> 2) | (vkey & 3);
  const int scb = skey >> 3, sci = skey & 7;
  const u16* gV = Xv + base + (size_t)vkey * D_MODEL + hd + wl * 16;

  bf16x8 bones;
#pragma unroll
  for (int i = 0; i < 8; ++i) bones[i] = (short)0x3F80;  // bf16 1.0

  f32x4 zero4 = {0.f, 0.f, 0.f, 0.f};
  int tcnt = 0;

  {
    const u16* gk0 = gK + (size_t)(half * 64) * D_MODEL;
    gload16(gk0, KtH + (wl * 16) * 64);
    gload16(gk0 + (size_t)8 * D_MODEL, KtH + (wl * 16 + 8) * 64);
  }
  const u16* gv0 = gV + (size_t)(half * 64) * D_MODEL;
  uint4 va0 = *(const uint4*)gv0;
  uint4 va1 = *(const uint4*)(gv0 + 8);

  for (int ph = 0; ph < 2; ++ph) {
    const int qt = ph ? xp : 15 - xp;
    const int q0 = qt << 7;
    const int rowb0 = q0 + wl * 32;

    bf16x8 bq[2][2];
#pragma unroll
    for (int mi = 0; mi < 2; ++mi)
#pragma unroll
      for (int ks = 0; ks < 2; ++ks)
        bq[mi][ks] = *(const bf16x8*)(Xq + base + (size_t)(rowb0 + mi * 16 + l15) * D_MODEL
                                      + hd + ks * 32 + quad * 8);

    f32x4 o[4][2], ol[2];
#pragma unroll
    for (int di = 0; di < 4; ++di)
#pragma unroll
      for (int mi = 0; mi < 2; ++mi) o[di][mi] = zero4;
#pragma unroll
    for (int mi = 0; mi < 2; ++mi) ol[mi] = zero4;

    const int cnt = qt + 1;

    if (ph == 1 && half == 1) {
      const int fb = tcnt & 1;
      const u16* gk1 = gK + (size_t)64 * D_MODEL;
      gload16(gk1, KtH + fb * 4096 + (wl * 16) * 64);
      gload16(gk1 + (size_t)8 * D_MODEL, KtH + fb * 4096 + (wl * 16 + 8) * 64);
    }

    for (int i = 0; i < cnt; ++i, ++tcnt) {
      const int k0 = (half + 2 * i) * 64;
      const int buf = tcnt & 1;
      u16* ktb = KtH + buf * 4096;
      u16* vtb = VtH + buf * 4096;

      {
        union { uint4 u; u16 hh[8]; } u0, u1;
        u0.u = va0; u1.u = va1;
#pragma unroll
        for (int ii = 0; ii < 8; ++ii) {
          vtb[(wl * 16 + ii) * 64 + ((scb ^ ii) << 3) + sci] = u0.hh[ii];
          vtb[(wl * 16 + 8 + ii) * 64 + ((scb ^ ii) << 3) + sci] = u1.hh[ii];
        }
      }
      __syncthreads();

      const bool inph = (i + 1 < cnt);
      if (inph || ph == 0) {
        const int k0n = inph ? k0 + 128 : half * 64;
        if (inph || half == 0) {
          const u16* gk2 = gK + (size_t)k0n * D_MODEL;
          u16* ktn = KtH + (1 - buf) * 4096;
          gload16(gk2, ktn + (wl * 16) * 64);
          gload16(gk2 + (size_t)8 * D_MODEL, ktn + (wl * 16 + 8) * 64);
        }
        const u16* gv2 = gV + (size_t)k0n * D_MODEL;
        va0 = *(const uint4*)gv2;
        va1 = *(const uint4*)(gv2 + 8);
      }

      f32x4 st[4][2];
#pragma unroll
      for (int ni = 0; ni < 4; ++ni) {
        const u16* kr = ktb + (ni * 16 + l15) * 64;
        bf16x8 a0 = *(const bf16x8*)(kr + ((quad ^ (l15 & 7)) << 3));
        bf16x8 a1 = *(const bf16x8*)(kr + (((4 + quad) ^ (l15 & 7)) << 3));
#pragma unroll
        for (int mi = 0; mi < 2; ++mi) {
          f32x4 t = zero4;
          t = __builtin_amdgcn_mfma_f32_16x16x32_bf16(a0, bq[mi][0], t, 0, 0, 0);
          t = __builtin_amdgcn_mfma_f32_16x16x32_bf16(a1, bq[mi][1], t, 0, 0, 0);
          st[ni][mi] = t;
        }
      }

      bf16x8 bp[2][2];
#pragma unroll
      for (int mi = 0; mi < 2; ++mi) {
        const int qa = rowb0 + mi * 16 + l15;
        if (k0 + 63 > rowb0 + mi * 16) {
#pragma unroll
          for (int ni = 0; ni < 4; ++ni)
#pragma unroll
            for (int r = 0; r < 4; ++r)
              if (k0 + ni * 16 + quad * 4 + r > qa) st[ni][mi][r] = -1e30f;
        }
        float p[4][4];
#pragma unroll
        for (int ni = 0; ni < 4; ++ni)
#pragma unroll
          for (int r = 0; r < 4; ++r)
            p[ni][r] = fexp2(st[ni][mi][r]);
#pragma unroll
        for (int js = 0; js < 2; ++js) {
          union { bf16x8 v; unsigned d[4]; } ub;
          ub.d[0] = cvtpk2(p[2 * js][0], p[2 * js][1]);
          ub.d[1] = cvtpk2(p[2 * js][2], p[2 * js][3]);
          ub.d[2] = cvtpk2(p[2 * js + 1][0], p[2 * js + 1][1]);
          ub.d[3] = cvtpk2(p[2 * js + 1][2], p[2 * js + 1][3]);
          bp[mi][js] = ub.v;
        }
      }

#pragma unroll
      for (int js = 0; js < 2; ++js) {
        bf16x8 av[4];
#pragma unroll
        for (int di = 0; di < 4; ++di)
          av[di] = *(const bf16x8*)(vtb + (di * 16 + l15) * 64
                                    + (((js * 4 + quad) ^ (l15 & 7)) << 3));
#pragma unroll
        for (int di = 0; di < 4; ++di)
#pragma unroll
          for (int mi = 0; mi < 2; ++mi)
            o[di][mi] = __builtin_amdgcn_mfma_f32_16x16x32_bf16(av[di], bp[mi][js], o[di][mi], 0, 0, 0);
#pragma unroll
        for (int mi = 0; mi < 2; ++mi)
          ol[mi] = __builtin_amdgcn_mfma_f32_16x16x32_bf16(bones, bp[mi][js], ol[mi], 0, 0, 0);
      }
    }

    __syncthreads();
    if (half == 1) {
#pragma unroll
      for (int mi = 0; mi < 2; ++mi) {
        const int ql = wl * 32 + mi * 16 + l15;
        if (quad == 0) ML[ql] = ol[mi][0];
#pragma unroll
        for (int di = 0; di < 4; ++di)
#pragma unroll
          for (int r = 0; r < 4; ++r) {
            const int d = di * 16 + quad * 4 + r;
            MO[ql * 64 + (d ^ ((ql & 7) << 3))] = o[di][mi][r];
          }
      }
    }
    __syncthreads();
    if (half == 0) {
#pragma unroll
      for (int mi = 0; mi < 2; ++mi) {
        const int ql = wl * 32 + mi * 16 + l15;
        const float inv = 1.0f / (ol[mi][0] + ML[ql]);
        const size_t qa = q0 + ql;
#pragma unroll
        for (int di = 0; di < 4; ++di) {
          float t[4];
#pragma unroll
          for (int r = 0; r < 4; ++r) {
            const int d = di * 16 + quad * 4 + r;
            t[r] = (o[di][mi][r] + MO[ql * 64 + (d ^ ((ql & 7) << 3))]) * inv;
          }
          uint2 s2;
          s2.x = cvtpk2(t[0], t[1]);
          s2.y = cvtpk2(t[2], t[3]);
          *(uint2*)(O + base + qa * D_MODEL + hd + di * 16 + quad * 4) = s2;
        }
      }
    }
    __syncthreads();
  }
}

// ---------------- launch ----------------
extern "C" void kernel_launch(void* const* d_in, const int* in_sizes, int n_in,
                              void* d_out, int out_size, void* d_ws, size_t ws_size,
                              hipStream_t stream) {
  const float* q   = (const float*)d_in[0];
  const float* k   = (const float*)d_in[1];
  const float* v   = (const float*)d_in[2];
  const float* w_q = (const float*)d_in[4];  const float* b_q = (const float*)d_in[5];
  const float* w_k = (const float*)d_in[6];  const float* b_k = (const float*)d_in[7];
  const float* w_v = (const float*)d_in[8];  const float* b_v = (const float*)d_in[9];
  const float* w_o = (const float*)d_in[10]; const float* b_o = (const float*)d_in[11];

  u16* ws = (u16*)d_ws;
  const size_t NTD = (size_t)NB * T_SEQ * D_MODEL;   // 8388608
  const size_t WSZ = (size_t)D_MODEL * D_MODEL;      // 1048576
  u16* wqb = ws;
  u16* wkb = wqb + WSZ;
  u16* wvb = wkb + WSZ;
  u16* wob = wvb + WSZ;
  u16* Xq  = wob + WSZ;
  u16* Xk  = Xq + NTD;
  u16* Xv  = Xk + NTD;
  u16* Ob  = Xv + NTD;
  // total ws: 4*2MB + 4*16.78MB = 75.5 MB

  cast_w4<<<dim3(WSZ / 1024, 4), 256, 0, stream>>>(w_q, w_k, w_v, w_o, wqb, wkb, wvb, wob);

  gemm_qkv<<<dim3(64, 8, 3), 256, 0, stream>>>(q, k, v, wqb, wkb, wvb,
                                               b_q, b_k, b_v, Xq, Xk, Xv);

  attn_fwd<<<dim3(8, NH, NB), 512, 0, stream>>>(Xq, Xk, Xv, Ob);

  gemm_nt_f32out<<<dim3(64, 8), 256, 0, stream>>>(Ob, wob, b_o, (float*)d_out,
                                                  8192, 1024, 1024);
}